// Round 1
// baseline (1161.455 us; speedup 1.0000x reference)
//
#include <hip/hip_runtime.h>
#include <math.h>

#define G 1024
#define NPG 512
#define NTOT (G*NPG)        // 524288
#define F 256
#define EDGES 8388608
#define EPG (EDGES/G)       // 8192 edges per graph, contiguous
#define KKEEP 256

// output layout (flat float32)
#define O_PX  ((size_t)0)
#define O_EI  ((size_t)67108864)   // G*K*F
#define O_EW  ((size_t)83886080)   // + 2*E
#define O_NGI ((size_t)92274688)   // + E

// ---- K1: h[i] = dot(x[i,:], w_gnn)  (one wave per row, float4 loads) ----
__global__ __launch_bounds__(256) void k_h(const float* __restrict__ x,
                                           const float* __restrict__ w,
                                           float* __restrict__ h) {
    int row  = blockIdx.x * 4 + (threadIdx.x >> 6);
    int lane = threadIdx.x & 63;
    const float4* x4 = (const float4*)x;
    const float4* w4 = (const float4*)w;
    float4 xv = x4[(size_t)row * 64 + lane];
    float4 wv = w4[lane];
    float s = xv.x*wv.x + xv.y*wv.y + xv.z*wv.z + xv.w*wv.w;
    #pragma unroll
    for (int off = 32; off > 0; off >>= 1) s += __shfl_down(s, off, 64);
    if (lane == 0) h[row] = s;
}

// ---- K2: per-graph: edge-ordered aggregation + tanh + top-K sort + outputs ----
__global__ __launch_bounds__(256) void k_agg_topk(
    const float* __restrict__ h,
    const int* __restrict__ src,
    const int* __restrict__ dst,
    const float* __restrict__ ew,
    const int* __restrict__ ngi,
    int* __restrict__ kept,
    float* __restrict__ kscore,
    int* __restrict__ new_id,
    float* __restrict__ out_ngi)
{
    __shared__ float    hloc[NPG];                 // 2 KB
    __shared__ unsigned cnt[NPG];                  // 2 KB
    __shared__ unsigned bufA[NPG];                 // 2 KB (scan ping)
    __shared__ unsigned bufB[NPG];                 // 2 KB (scan pong)
    __shared__ unsigned cursor[NPG];               // 2 KB
    __shared__ float    score[NPG];                // 2 KB
    __shared__ __align__(16) float c_arr[EPG];     // 32 KB (keys overlay later)
    __shared__ unsigned short slot[EPG];           // 16 KB   => 60 KB total

    const int tid = threadIdx.x;
    const int g = blockIdx.x;
    const int base_n = g * NPG;
    const size_t base_e = (size_t)g * EPG;

    for (int i = tid; i < NPG; i += 256) { hloc[i] = h[base_n + i]; cnt[i] = 0; }
    __syncthreads();

    // count in-degree + per-edge contribution c = ew * h[src] (f32 product, matches np)
    #pragma unroll 4
    for (int k = 0; k < EPG/256; ++k) {
        int e = k*256 + tid;
        int s = src[base_e + e] - base_n;
        int d = dst[base_e + e] - base_n;
        c_arr[e] = ew[base_e + e] * hloc[s];
        atomicAdd(&cnt[d], 1u);
    }
    __syncthreads();

    // Hillis-Steele inclusive scan of cnt (512 elems, double buffered)
    for (int i = tid; i < NPG; i += 256) bufA[i] = cnt[i];
    __syncthreads();
    unsigned* A = bufA; unsigned* B = bufB;
    for (int step = 1; step < NPG; step <<= 1) {
        for (int i = tid; i < NPG; i += 256)
            B[i] = A[i] + ((i >= step) ? A[i - step] : 0u);
        __syncthreads();
        unsigned* t = A; A = B; B = t;
    }
    // exclusive starts into B; cursors too
    for (int i = tid; i < NPG; i += 256) {
        unsigned st = A[i] - cnt[i];
        B[i] = st;
        cursor[i] = st;
    }
    __syncthreads();
    unsigned* startp = B;

    // CSR placement (row order irrelevant — int atomics, deterministic sets)
    #pragma unroll 4
    for (int k = 0; k < EPG/256; ++k) {
        int e = k*256 + tid;
        int d = dst[base_e + e] - base_n;
        unsigned pos = atomicAdd(&cursor[d], 1u);
        slot[pos] = (unsigned short)e;
    }
    __syncthreads();

    // per-node sum in INCREASING edge order (matches np.add.at order exactly)
    for (int d = tid; d < NPG; d += 256) {
        unsigned s0 = startp[d];
        unsigned c  = cnt[d];
        float s = 0.0f;
        int prev = -1;
        for (unsigned k2 = 0; k2 < c; ++k2) {
            int m = 1 << 30;
            for (unsigned j = 0; j < c; ++j) {
                int v = (int)slot[s0 + j];
                if (v > prev && v < m) m = v;
            }
            s += c_arr[m];
            prev = m;
        }
        score[d] = (float)tanh((double)(s + hloc[d]));
    }
    __syncthreads();

    // pack keys: (ordered float bits)<<32 | (511 - idx)  -> ascending bitonic sort
    unsigned long long* keys = (unsigned long long*)c_arr;
    for (int i = tid; i < NPG; i += 256) {
        unsigned u = __float_as_uint(score[i]);
        unsigned ord = ((int)u < 0) ? ~u : (u ^ 0x80000000u);
        keys[i] = ((unsigned long long)ord << 32) | (unsigned)(NPG - 1 - i);
    }
    __syncthreads();

    for (int k = 2; k <= NPG; k <<= 1) {
        for (int j = k >> 1; j > 0; j >>= 1) {
            #pragma unroll
            for (int r = 0; r < 2; ++r) {
                int i = tid + r*256;
                int ixj = i ^ j;
                if (ixj > i) {
                    unsigned long long a = keys[i], b = keys[ixj];
                    bool up = ((i & k) == 0);
                    if ((a > b) == up) { keys[i] = b; keys[ixj] = a; }
                }
            }
            __syncthreads();
        }
    }

    // emit top-K (descending = read sorted array from the top)
    {
        int i = tid;  // 0..255 == K
        unsigned long long kk = keys[NPG - 1 - i];
        int lidx = NPG - 1 - (int)(kk & 0xFFFFFFFFULL);
        int oldg = base_n + lidx;
        int nw = g * KKEEP + i;
        kept[nw] = oldg;
        kscore[nw] = score[lidx];
        new_id[oldg] = nw;
        out_ngi[nw] = (float)ngi[oldg];
    }
}

// ---- K3: pooled_x = x[kept] * score  (one wave per row) ----
__global__ __launch_bounds__(256) void k_gather(
    const float* __restrict__ x,
    const int* __restrict__ kept,
    const float* __restrict__ kscore,
    float* __restrict__ out_px)
{
    int r    = blockIdx.x * 4 + (threadIdx.x >> 6);
    int lane = threadIdx.x & 63;
    int old  = kept[r];
    float sc = kscore[r];
    const float4* x4 = (const float4*)x;
    float4* o4 = (float4*)out_px;
    float4 v = x4[(size_t)old * 64 + lane];
    v.x *= sc; v.y *= sc; v.z *= sc; v.w *= sc;
    o4[(size_t)r * 64 + lane] = v;
}

// ---- K4: edge remap + mask, ints written as floats ----
__global__ __launch_bounds__(256) void k_remap(
    const int* __restrict__ src,
    const int* __restrict__ dst,
    const float* __restrict__ ew,
    const int* __restrict__ new_id,
    float* __restrict__ out)
{
    size_t t = (size_t)blockIdx.x * 256 + threadIdx.x;   // one int4/float4 per thread
    const int4*   s4 = (const int4*)src;
    const int4*   d4 = (const int4*)dst;
    const float4* w4 = (const float4*)ew;
    int4 s = s4[t], d = d4[t];
    float4 w = w4[t];
    int ns0 = new_id[s.x], ns1 = new_id[s.y], ns2 = new_id[s.z], ns3 = new_id[s.w];
    int nd0 = new_id[d.x], nd1 = new_id[d.y], nd2 = new_id[d.z], nd3 = new_id[d.w];
    bool v0 = (ns0 >= 0) && (nd0 >= 0);
    bool v1 = (ns1 >= 0) && (nd1 >= 0);
    bool v2 = (ns2 >= 0) && (nd2 >= 0);
    bool v3 = (ns3 >= 0) && (nd3 >= 0);
    float4 os = { v0 ? (float)ns0 : 0.0f, v1 ? (float)ns1 : 0.0f,
                  v2 ? (float)ns2 : 0.0f, v3 ? (float)ns3 : 0.0f };
    float4 od = { v0 ? (float)nd0 : 0.0f, v1 ? (float)nd1 : 0.0f,
                  v2 ? (float)nd2 : 0.0f, v3 ? (float)nd3 : 0.0f };
    float4 ow = { v0 ? w.x : 0.0f, v1 ? w.y : 0.0f,
                  v2 ? w.z : 0.0f, v3 ? w.w : 0.0f };
    ((float4*)(out + O_EI))[t]         = os;
    ((float4*)(out + O_EI + EDGES))[t] = od;
    ((float4*)(out + O_EW))[t]         = ow;
}

extern "C" void kernel_launch(void* const* d_in, const int* in_sizes, int n_in,
                              void* d_out, int out_size, void* d_ws, size_t ws_size,
                              hipStream_t stream) {
    const float* x   = (const float*)d_in[0];
    const int*   ei  = (const int*)d_in[1];     // [2,E]: row0=src, row1=dst
    const float* ew  = (const float*)d_in[2];
    const int*   ngi = (const int*)d_in[3];
    const float* w   = (const float*)d_in[4];
    float* out = (float*)d_out;

    char* ws = (char*)d_ws;
    float* h      = (float*)(ws);                                  // N f32
    int*   kept   = (int*)  (ws + (size_t)NTOT*4);                 // G*K i32
    float* kscore = (float*)(ws + (size_t)NTOT*4 + (size_t)G*KKEEP*4);
    int*   new_id = (int*)  (ws + (size_t)NTOT*4 + (size_t)G*KKEEP*8);  // N i32

    hipMemsetAsync(new_id, 0xFF, (size_t)NTOT*4, stream);          // -1 everywhere
    k_h       <<<NTOT/4,        256, 0, stream>>>(x, w, h);
    k_agg_topk<<<G,             256, 0, stream>>>(h, ei, ei + EDGES, ew, ngi,
                                                  kept, kscore, new_id, out + O_NGI);
    k_gather  <<<G*KKEEP/4,     256, 0, stream>>>(x, kept, kscore, out + O_PX);
    k_remap   <<<EDGES/1024,    256, 0, stream>>>(ei, ei + EDGES, ew, new_id, out);
}